// Round 4
// baseline (555.298 us; speedup 1.0000x reference)
//
#include <hip/hip_runtime.h>

#define N_NODES 100000
#define N_EDGES 800000
#define DIM 64
#define BN_EPS 1e-5f

// ===========================================================================
// CSR build: count in-degrees, exclusive scan, scatter edges grouped by dst.
// Edge payload packed as int2 {src, bits(w)}.
// ===========================================================================

__global__ __launch_bounds__(256) void k_zero_deg(int* __restrict__ deg) {
    int i = blockIdx.x * blockDim.x + threadIdx.x;
    if (i < N_NODES) deg[i] = 0;
}

__global__ __launch_bounds__(256) void k_count(const int* __restrict__ dst,
                                               int* __restrict__ deg) {
    int e = blockIdx.x * blockDim.x + threadIdx.x;
    if (e < N_EDGES) atomicAdd(&deg[dst[e]], 1);
}

// 98 blocks x 256 threads x 4 elems = 100352 >= N. Per-block exclusive scan.
__global__ __launch_bounds__(256) void k_scan1(const int* __restrict__ deg,
                                               int* __restrict__ row_off,
                                               int* __restrict__ block_sums) {
    __shared__ int sdata[256];
    int tid = threadIdx.x;
    int base = blockIdx.x * 1024 + tid * 4;
    int4 v = make_int4(0, 0, 0, 0);
    if (base < N_NODES) v = *(const int4*)(deg + base);   // N % 4 == 0
    int tsum = v.x + v.y + v.z + v.w;
    sdata[tid] = tsum;
    __syncthreads();
    for (int off = 1; off < 256; off <<= 1) {
        int t = (tid >= off) ? sdata[tid - off] : 0;
        __syncthreads();
        sdata[tid] += t;
        __syncthreads();
    }
    int excl = sdata[tid] - tsum;
    if (base < N_NODES) {
        int4 o;
        o.x = excl;
        o.y = o.x + v.x;
        o.z = o.y + v.y;
        o.w = o.z + v.z;
        *(int4*)(row_off + base) = o;
    }
    if (tid == 255) block_sums[blockIdx.x] = sdata[255];
}

__global__ __launch_bounds__(128) void k_scan2(int* __restrict__ block_sums) {
    __shared__ int sdata[128];
    int tid = threadIdx.x;
    int v = (tid < 98) ? block_sums[tid] : 0;
    sdata[tid] = v;
    __syncthreads();
    for (int off = 1; off < 128; off <<= 1) {
        int t = (tid >= off) ? sdata[tid - off] : 0;
        __syncthreads();
        sdata[tid] += t;
        __syncthreads();
    }
    if (tid < 98) block_sums[tid] = sdata[tid] - v;
}

__global__ __launch_bounds__(256) void k_scan3(const int* __restrict__ deg,
                                               int* __restrict__ row_off,
                                               int* __restrict__ cursor,
                                               float* __restrict__ dinv,
                                               const int* __restrict__ block_sums) {
    int tid = threadIdx.x;
    int base = blockIdx.x * 1024 + tid * 4;
    if (base >= N_NODES) return;
    int p = block_sums[blockIdx.x];
    int4 r = *(const int4*)(row_off + base);
    r.x += p; r.y += p; r.z += p; r.w += p;
    *(int4*)(row_off + base) = r;
    *(int4*)(cursor + base) = r;
    int4 d = *(const int4*)(deg + base);
    float4 di;
    di.x = rsqrtf((float)(d.x + 1));
    di.y = rsqrtf((float)(d.y + 1));
    di.z = rsqrtf((float)(d.z + 1));
    di.w = rsqrtf((float)(d.w + 1));
    *(float4*)(dinv + base) = di;
}

__global__ __launch_bounds__(256) void k_build(const int* __restrict__ ei,
                                               const float* __restrict__ dinv,
                                               int* __restrict__ cursor,
                                               int2* __restrict__ edges) {
    int e = blockIdx.x * blockDim.x + threadIdx.x;
    if (e >= N_EDGES) return;
    int s = ei[e];
    int d = ei[N_EDGES + e];
    int pos = atomicAdd(&cursor[d], 1);
    edges[pos] = make_int2(s, __float_as_int(dinv[s] * dinv[d]));
}

// ===========================================================================
// Aggregation: quarter-wave (16 lanes) per node, lane covers a float4 chunk.
// One vmem instr gathers 4 nodes' edge rows; 4 independent edge streams
// per wave + 4-deep unroll = high memory-level parallelism. No atomics.
// out[n] = dinv[n]^2 * x[n] + sum_e w_e * x[src_e]
// ===========================================================================
__global__ __launch_bounds__(256) void k_aggregate(const float* __restrict__ xin,
                                                   const int* __restrict__ row_off,
                                                   const int* __restrict__ deg,
                                                   const int2* __restrict__ edges,
                                                   const float* __restrict__ dinv,
                                                   float* __restrict__ out) {
    int tid = threadIdx.x;
    int q = tid & 15;                       // float4 chunk within row
    int node = blockIdx.x * 16 + (tid >> 4);  // grid = 6250, exact
    float di = dinv[node];
    float4 acc = ((const float4*)(xin + (size_t)node * DIM))[q];
    float w0 = di * di;
    acc.x *= w0; acc.y *= w0; acc.z *= w0; acc.w *= w0;

    int beg = row_off[node];
    int len = deg[node];
    int k = 0;
    for (; k + 4 <= len; k += 4) {
        int2 e0 = edges[beg + k + 0];
        int2 e1 = edges[beg + k + 1];
        int2 e2 = edges[beg + k + 2];
        int2 e3 = edges[beg + k + 3];
        float4 v0 = ((const float4*)(xin + (size_t)e0.x * DIM))[q];
        float4 v1 = ((const float4*)(xin + (size_t)e1.x * DIM))[q];
        float4 v2 = ((const float4*)(xin + (size_t)e2.x * DIM))[q];
        float4 v3 = ((const float4*)(xin + (size_t)e3.x * DIM))[q];
        float w1 = __int_as_float(e0.y), w2 = __int_as_float(e1.y);
        float w3 = __int_as_float(e2.y), w4 = __int_as_float(e3.y);
        acc.x = fmaf(w1, v0.x, acc.x); acc.y = fmaf(w1, v0.y, acc.y);
        acc.z = fmaf(w1, v0.z, acc.z); acc.w = fmaf(w1, v0.w, acc.w);
        acc.x = fmaf(w2, v1.x, acc.x); acc.y = fmaf(w2, v1.y, acc.y);
        acc.z = fmaf(w2, v1.z, acc.z); acc.w = fmaf(w2, v1.w, acc.w);
        acc.x = fmaf(w3, v2.x, acc.x); acc.y = fmaf(w3, v2.y, acc.y);
        acc.z = fmaf(w3, v2.z, acc.z); acc.w = fmaf(w3, v2.w, acc.w);
        acc.x = fmaf(w4, v3.x, acc.x); acc.y = fmaf(w4, v3.y, acc.y);
        acc.z = fmaf(w4, v3.z, acc.z); acc.w = fmaf(w4, v3.w, acc.w);
    }
    for (; k < len; ++k) {
        int2 e = edges[beg + k];
        float4 v = ((const float4*)(xin + (size_t)e.x * DIM))[q];
        float w = __int_as_float(e.y);
        acc.x = fmaf(w, v.x, acc.x); acc.y = fmaf(w, v.y, acc.y);
        acc.z = fmaf(w, v.z, acc.z); acc.w = fmaf(w, v.w, acc.w);
    }
    ((float4*)(out + (size_t)node * DIM))[q] = acc;
}

// ===========================================================================
// GEMM + BN + ReLU: lane = output column. W column in 64 VGPRs (loaded once,
// coalesced); x row values are wave-uniform -> scalar (s_load) broadcasts.
// out[r][c] = relu( (sum_k x[r][k]*W[k][c] + bias[c] - m[c])*s[c] + b[c] )
// Block = 1 wave = 64 threads; 64 rows per block. No LDS, no bank conflicts.
// ===========================================================================
__global__ __launch_bounds__(64) void k_gemm_bn(const float* __restrict__ xin,
                                                const float* __restrict__ W,
                                                const float* __restrict__ bias,
                                                const float* __restrict__ bng,
                                                const float* __restrict__ bnb,
                                                const float* __restrict__ bnm,
                                                const float* __restrict__ bnv,
                                                float* __restrict__ out) {
    int lane = threadIdx.x;
    float wcol[64];
#pragma unroll
    for (int k = 0; k < 64; ++k) wcol[k] = W[k * 64 + lane];
    float A = bng[lane] * rsqrtf(bnv[lane] + BN_EPS);
    float B = (bias[lane] - bnm[lane]) * A + bnb[lane];

    int row0 = blockIdx.x * 64;
    int rend = min(64, N_NODES - row0);
#pragma unroll 2
    for (int r = 0; r < rend; ++r) {
        const float* xr = xin + (size_t)(row0 + r) * DIM;
        float a0 = 0.f, a1 = 0.f, a2 = 0.f, a3 = 0.f;
#pragma unroll
        for (int k = 0; k < 64; k += 4) {
            a0 = fmaf(xr[k + 0], wcol[k + 0], a0);
            a1 = fmaf(xr[k + 1], wcol[k + 1], a1);
            a2 = fmaf(xr[k + 2], wcol[k + 2], a2);
            a3 = fmaf(xr[k + 3], wcol[k + 3], a3);
        }
        float h = (a0 + a1) + (a2 + a3);
        out[(size_t)(row0 + r) * DIM + lane] = fmaxf(0.f, fmaf(h, A, B));
    }
}

// ===========================================================================
// Layer-3 GEMM + predictor MLP fused, all in registers:
// out = tanh( (x@W3+b3) @ pW1 + pb1 ) @ pW2 + pb2
// Three W columns live in VGPRs (192). Cross-lane row handoff via a 256 B
// LDS row buffer read back as broadcast float4 (conflict-free).
// ===========================================================================
__global__ __launch_bounds__(64) void k_l3_mlp(const float* __restrict__ xin,
                                               const float* __restrict__ W3,
                                               const float* __restrict__ b3,
                                               const float* __restrict__ pW1,
                                               const float* __restrict__ pb1,
                                               const float* __restrict__ pW2,
                                               const float* __restrict__ pb2,
                                               float* __restrict__ out) {
    __shared__ float srowA[64];
    __shared__ float srowB[64];
    int lane = threadIdx.x;
    float w3c[64], w1c[64], w2c[64];
#pragma unroll
    for (int k = 0; k < 64; ++k) w3c[k] = W3[k * 64 + lane];
#pragma unroll
    for (int k = 0; k < 64; ++k) w1c[k] = pW1[k * 64 + lane];
#pragma unroll
    for (int k = 0; k < 64; ++k) w2c[k] = pW2[k * 64 + lane];
    float vb3 = b3[lane], vb1 = pb1[lane], vb2 = pb2[lane];

    int row0 = blockIdx.x * 64;
    int rend = min(64, N_NODES - row0);
    for (int r = 0; r < rend; ++r) {
        const float* xr = xin + (size_t)(row0 + r) * DIM;
        // GEMM1: x row (uniform scalar) x W3 cols (VGPR)
        float a0 = 0.f, a1 = 0.f, a2 = 0.f, a3 = 0.f;
#pragma unroll
        for (int k = 0; k < 64; k += 4) {
            a0 = fmaf(xr[k + 0], w3c[k + 0], a0);
            a1 = fmaf(xr[k + 1], w3c[k + 1], a1);
            a2 = fmaf(xr[k + 2], w3c[k + 2], a2);
            a3 = fmaf(xr[k + 3], w3c[k + 3], a3);
        }
        srowA[lane] = (a0 + a1) + (a2 + a3) + vb3;
        __syncthreads();
        // GEMM2: broadcast h row from LDS (float4), pW1 cols in VGPR
        const float4* sa4 = (const float4*)srowA;
        float b0 = 0.f, b1v = 0.f, b2v = 0.f, b3v = 0.f;
#pragma unroll
        for (int k4 = 0; k4 < 16; ++k4) {
            float4 xv = sa4[k4];
            b0  = fmaf(xv.x, w1c[k4 * 4 + 0], b0);
            b1v = fmaf(xv.y, w1c[k4 * 4 + 1], b1v);
            b2v = fmaf(xv.z, w1c[k4 * 4 + 2], b2v);
            b3v = fmaf(xv.w, w1c[k4 * 4 + 3], b3v);
        }
        srowB[lane] = tanhf((b0 + b1v) + (b2v + b3v) + vb1);
        __syncthreads();
        // GEMM3: broadcast tanh row, pW2 cols in VGPR
        const float4* sb4 = (const float4*)srowB;
        float c0 = 0.f, c1 = 0.f, c2 = 0.f, c3 = 0.f;
#pragma unroll
        for (int k4 = 0; k4 < 16; ++k4) {
            float4 xv = sb4[k4];
            c0 = fmaf(xv.x, w2c[k4 * 4 + 0], c0);
            c1 = fmaf(xv.y, w2c[k4 * 4 + 1], c1);
            c2 = fmaf(xv.z, w2c[k4 * 4 + 2], c2);
            c3 = fmaf(xv.w, w2c[k4 * 4 + 3], c3);
        }
        out[(size_t)(row0 + r) * DIM + lane] = (c0 + c1) + (c2 + c3) + vb2;
    }
}

// ===========================================================================
extern "C" void kernel_launch(void* const* d_in, const int* in_sizes, int n_in,
                              void* d_out, int out_size, void* d_ws, size_t ws_size,
                              hipStream_t stream) {
    const float* x     = (const float*)d_in[0];
    const int*   ei    = (const int*)d_in[1];
    const float* W1    = (const float*)d_in[2];
    const float* b1    = (const float*)d_in[3];
    const float* W2    = (const float*)d_in[4];
    const float* b2    = (const float*)d_in[5];
    const float* W3    = (const float*)d_in[6];
    const float* b3    = (const float*)d_in[7];
    const float* bn1_g = (const float*)d_in[8];
    const float* bn1_b = (const float*)d_in[9];
    const float* bn1_m = (const float*)d_in[10];
    const float* bn1_v = (const float*)d_in[11];
    const float* bn2_g = (const float*)d_in[12];
    const float* bn2_b = (const float*)d_in[13];
    const float* bn2_m = (const float*)d_in[14];
    const float* bn2_v = (const float*)d_in[15];
    const float* pW1   = (const float*)d_in[16];
    const float* pb1   = (const float*)d_in[17];
    const float* pW2   = (const float*)d_in[18];
    const float* pb2   = (const float*)d_in[19];
    float* out = (float*)d_out;

    char* ws = (char*)d_ws;
    int*   deg      = (int*)ws;                      ws += 100352 * 4;
    int*   row_off  = (int*)ws;                      ws += 100352 * 4;
    int*   cursor   = (int*)ws;                      ws += 100352 * 4;
    int*   bsums    = (int*)ws;                      ws += 128 * 4;
    int2*  edges    = (int2*)ws;                     ws += (size_t)N_EDGES * 8;
    float* dinv     = (float*)ws;                    ws += 100352 * 4;
    float* bufA     = (float*)ws;                    ws += (size_t)N_NODES * DIM * 4;
    float* bufB     = (float*)ws;

    const int blk = 256;
    int gN    = (N_NODES + blk - 1) / blk;       // 391
    int gE    = (N_EDGES + blk - 1) / blk;       // 3125
    int gScan = 98;
    int gAgg  = N_NODES / 16;                    // 6250 (exact)
    int gRow  = (N_NODES + 63) / 64;             // 1563

    // ---- CSR build (once, reused by all 3 layers) ----
    k_zero_deg<<<gN, blk, 0, stream>>>(deg);
    k_count<<<gE, blk, 0, stream>>>(ei + N_EDGES, deg);
    k_scan1<<<gScan, blk, 0, stream>>>(deg, row_off, bsums);
    k_scan2<<<1, 128, 0, stream>>>(bsums);
    k_scan3<<<gScan, blk, 0, stream>>>(deg, row_off, cursor, dinv, bsums);
    k_build<<<gE, blk, 0, stream>>>(ei, dinv, cursor, edges);

    // ---- layer 1 ----
    k_aggregate<<<gAgg, blk, 0, stream>>>(x, row_off, deg, edges, dinv, bufA);
    k_gemm_bn<<<gRow, 64, 0, stream>>>(bufA, W1, b1, bn1_g, bn1_b, bn1_m, bn1_v, bufB);

    // ---- layer 2 ----
    k_aggregate<<<gAgg, blk, 0, stream>>>(bufB, row_off, deg, edges, dinv, bufA);
    k_gemm_bn<<<gRow, 64, 0, stream>>>(bufA, W2, b2, bn2_g, bn2_b, bn2_m, bn2_v, bufB);

    // ---- layer 3 + predictor MLP ----
    k_aggregate<<<gAgg, blk, 0, stream>>>(bufB, row_off, deg, edges, dinv, bufA);
    k_l3_mlp<<<gRow, 64, 0, stream>>>(bufA, W3, b3, pW1, pb1, pW2, pb2, out);
}